// Round 12
// baseline (383.454 us; speedup 1.0000x reference)
//
#include <hip/hip_runtime.h>

#define NUM_ITERS 500
#define LR_F 0.001f
#define VPLANE 262144    // 4*64*1024 floats
// K=1 Krylov truncation: s = d0*v0, d0 = 500*LR/||v0||.
// R20: k_prep removed, Gam block partials GOOD; atomic epilogue BAD.
// R21: LDS pitch-skew ~NEUTRAL. R22: register-direct conv WIN 147.7->118.4.
// R23: dword-halo + 8px/thread REGRESSED (TA pipe). R24: och-pairing WIN
//      205.5->114.9. R25: explicit load pipeline NEUTRAL. R27: DPP halo
//      ~NEUTRAL (113.8) -> conv inner loop is NOT the bottleneck; ~114us is
//      dominated by 5 inter-kernel drain/launch epochs + small kernels.
// R26: hipLaunchCooperativeKernel FAILED (graph capture). DO NOT re-attempt
//      the cooperative API.
// R28: persistent fused kernel FAILED TO COMPILE (__hip_atomic_fence absent).
// R30: fences -> __threadfence(); UNMEASURED (broker timeout R11).
// R31 (this round): resubmit R30 verbatim. 512 blocks @ launch_bounds(256,2)
//      all co-resident; 5 device barriers (bounded spin: co-residency failure
//      => wrong answer, never a hang) replace 5 launch/drain epochs.
//      Stage bodies verbatim R27 (passing, absmax 0.015625).

// ---- DPP lane+-1 within 16-lane rows (boundary lanes masked by caller) ------
__device__ __forceinline__ float dpp_shr1(float v) {   // lane L <- lane L-1
  int r = __builtin_amdgcn_update_dpp(0, __float_as_int(v), 0x111, 0xf, 0xf, true);
  return __int_as_float(r);
}
__device__ __forceinline__ float dpp_shl1(float v) {   // lane L <- lane L+1
  int r = __builtin_amdgcn_update_dpp(0, __float_as_int(v), 0x101, 0xf, 0xf, true);
  return __int_as_float(r);
}

// ---- device-wide barrier (persistent kernel, 512 arrivals/phase) ------------
__device__ __forceinline__ void gbar(unsigned* __restrict__ Bar, unsigned phase) {
  __syncthreads();                              // block done with its stores
  if (threadIdx.x == 0) {
    __threadfence();                            // agent release: L2 writeback
    __hip_atomic_fetch_add(Bar, 1u, __ATOMIC_RELAXED, __HIP_MEMORY_SCOPE_AGENT);
    unsigned target = 512u * phase;
    for (int it = 0; it < (1 << 20); ++it) {    // bounded: no infinite hang
      if (__hip_atomic_load(Bar, __ATOMIC_RELAXED, __HIP_MEMORY_SCOPE_AGENT) >= target)
        break;
      __builtin_amdgcn_s_sleep(8);
    }
    __threadfence();                            // agent acquire: L1/L2 inv
  }
  __syncthreads();                              // rest of block waits on t0
}

// ---- raw weight loads (wave-uniform addresses -> s_load) --------------------
__device__ __forceinline__ void wldI(const float* __restrict__ Wff,
                                     const float* __restrict__ Wb,
                                     int oc, float w[10]) {
  const float* s = Wff + (size_t)oc * 9;
#pragma unroll
  for (int k = 0; k < 9; ++k) w[k] = s[k];
  w[9] = Wb[oc];
}
__device__ __forceinline__ void wldF(const float* __restrict__ Wfb,
                                     int ci, int och, float w[10]) {
  const float* s = Wfb + ((size_t)ci * 64 + och) * 9;
#pragma unroll
  for (int k = 0; k < 9; ++k) w[k] = s[k];
  w[9] = 0.f;
}
__device__ __forceinline__ void wldZ(const float* __restrict__ Wfb,
                                     int co, int ci, float w[10]) {
  const float* s = Wfb + ((size_t)co * 64 + ci) * 9;
#pragma unroll
  for (int k = 0; k < 9; ++k) w[k] = s[8 - k];
  w[9] = 0.f;
}

// ---- load_rows6 + compute16x2 (R27 conv core, FP order unchanged) -----------
__device__ __forceinline__ void load_rows6(const float* __restrict__ plane,
                                           int strip4, int cg4, float4 r[6]) {
  int R0 = strip4 == 0 ? 0 : strip4 - 1;
  int R5 = strip4 == 28 ? 31 : strip4 + 4;
  r[0] = *(const float4*)(plane + R0 * 32 + cg4);
#pragma unroll
  for (int rr = 1; rr < 5; ++rr)
    r[rr] = *(const float4*)(plane + (strip4 + rr - 1) * 32 + cg4);
  r[5] = *(const float4*)(plane + R5 * 32 + cg4);
}

template <bool BYP, bool SCALE>
__device__ __forceinline__ void compute16x2(const float4 rin[6],
                                            const float w0[10], const float w1[10],
                                            float d0, int strip4,
                                            bool cg0, bool cg7,
                                            float acc0[16], float acc1[16],
                                            float by0[16], float by1[16]) {
  float wb0 = w0[9], wb1 = w1[9];
#pragma unroll
  for (int r = 0; r < 6; ++r) {
    float4 f4 = rin[r];
    if (r == 0) {
      bool ok = strip4 > 0;
      f4.x = ok ? f4.x : 0.f; f4.y = ok ? f4.y : 0.f;
      f4.z = ok ? f4.z : 0.f; f4.w = ok ? f4.w : 0.f;
    }
    if (r == 5) {
      bool ok = strip4 < 28;
      f4.x = ok ? f4.x : 0.f; f4.y = ok ? f4.y : 0.f;
      f4.z = ok ? f4.z : 0.f; f4.w = ok ? f4.w : 0.f;
    }
    if (SCALE) { f4.x *= d0; f4.y *= d0; f4.z *= d0; f4.w *= d0; }
    float fl = dpp_shr1(f4.w);   // lane-1's col 4cg+3 == our 4cg-1
    float fr = dpp_shl1(f4.x);   // lane+1's col 4cg   == our 4cg+4
    fl = cg0 ? 0.f : fl;
    fr = cg7 ? 0.f : fr;
    float fv[6] = {fl, f4.x, f4.y, f4.z, f4.w, fr};
#pragma unroll
    for (int k = 0; k < 4; ++k) {
      int di = r - k;
      if (di >= 0 && di < 3) {
#pragma unroll
        for (int dj = 0; dj < 3; ++dj) {
          float wv0 = w0[di * 3 + dj];
          float wv1 = w1[di * 3 + dj];
#pragma unroll
          for (int c = 0; c < 4; ++c) {
            acc0[k * 4 + c] = fmaf(fv[c + dj], wv0, acc0[k * 4 + c]);
            acc1[k * 4 + c] = fmaf(fv[c + dj], wv1, acc1[k * 4 + c]);
          }
        }
        if (BYP && di == 1) {
#pragma unroll
          for (int c = 0; c < 4; ++c) {
            by0[k * 4 + c] = fmaf(fv[c + 1], wb0, by0[k * 4 + c]);
            by1[k * 4 + c] = fmaf(fv[c + 1], wb1, by1[k * 4 + c]);
          }
        }
      }
    }
  }
}

// ---- fused persistent kernel: 512 blocks x 256 thr, 2 blocks/CU -------------
__global__ __launch_bounds__(256, 2) void k_fused(const float* __restrict__ x,
                                                  const float* __restrict__ Wff,
                                                  const float* __restrict__ Wfb,
                                                  const float* __restrict__ Wb,
                                                  float* __restrict__ out,
                                                  float* __restrict__ V,
                                                  float* __restrict__ Gam,
                                                  float* __restrict__ PA,
                                                  float* __restrict__ Q,
                                                  float* __restrict__ Bq,
                                                  float* __restrict__ Fp,
                                                  float* __restrict__ Y,
                                                  unsigned* __restrict__ Bar) {
  __shared__ float ws[4];
  int tid = threadIdx.x, blk = blockIdx.x;
  int wv = __builtin_amdgcn_readfirstlane(tid >> 6);
  int strip4 = ((tid >> 3) & 7) * 4;
  int cg4 = (tid & 7) * 4;
  bool cg0 = (tid & 7) == 0, cg7 = (tid & 7) == 7;

  // ---- stage A: init — Q,Bq partials over 8-ci octant -----------------------
  {
    int ciO = blk & 7, ochP = (blk >> 3) & 15, b = blk >> 7;
    int och0 = ochP * 8 + wv * 2;
    const float* pb = x + (size_t)(b * 64 + ciO * 8) * 1024;
    int oc0 = och0 * 64 + ciO * 8, oc1 = oc0 + 64;
    float wA0[10], wA1[10], wB0[10], wB1[10];
    float4 rA[6], rB[6];
    float acc0[16], acc1[16], by0[16], by1[16];
#pragma unroll
    for (int i = 0; i < 16; ++i) { acc0[i] = 0.f; acc1[i] = 0.f; by0[i] = 0.f; by1[i] = 0.f; }
    load_rows6(pb, strip4, cg4, rA);
    wldI(Wff, Wb, oc0, wA0);
    wldI(Wff, Wb, oc1, wA1);
    for (int ci = 0; ci < 8; ci += 2) {
      load_rows6(pb + (size_t)(ci + 1) * 1024, strip4, cg4, rB);
      wldI(Wff, Wb, oc0 + ci + 1, wB0);
      wldI(Wff, Wb, oc1 + ci + 1, wB1);
      compute16x2<true, false>(rA, wA0, wA1, 0.f, strip4, cg0, cg7, acc0, acc1, by0, by1);
      if (ci + 2 < 8) {
        load_rows6(pb + (size_t)(ci + 2) * 1024, strip4, cg4, rA);
        wldI(Wff, Wb, oc0 + ci + 2, wA0);
        wldI(Wff, Wb, oc1 + ci + 2, wA1);
      }
      compute16x2<true, false>(rB, wB0, wB1, 0.f, strip4, cg0, cg7, acc0, acc1, by0, by1);
    }
    size_t off = (size_t)ciO * 524288 + (size_t)(b * 128 + och0) * 1024 + strip4 * 32 + cg4;
#pragma unroll
    for (int k = 0; k < 4; ++k) {
      *(float4*)(Q  + off + k * 32) = {acc0[k*4], acc0[k*4+1], acc0[k*4+2], acc0[k*4+3]};
      *(float4*)(Bq + off + k * 32) = {by0[k*4],  by0[k*4+1],  by0[k*4+2],  by0[k*4+3]};
      *(float4*)(Q  + off + 1024 + k * 32) = {acc1[k*4], acc1[k*4+1], acc1[k*4+2], acc1[k*4+3]};
      *(float4*)(Bq + off + 1024 + k * 32) = {by1[k*4],  by1[k*4+1],  by1[k*4+2],  by1[k*4+3]};
    }
  }
  gbar(Bar, 1);

  // ---- stage B: Y = relu(sum8 Q); out-base = Y + sum8 Bq --------------------
  {
    size_t i = (size_t)(blk * 256 + tid) * 4;
    float4 qs = {0.f, 0.f, 0.f, 0.f}, bs = {0.f, 0.f, 0.f, 0.f};
#pragma unroll
    for (int q = 0; q < 8; ++q) {
      float4 a = *(const float4*)(Q + (size_t)q * 524288 + i);
      float4 c = *(const float4*)(Bq + (size_t)q * 524288 + i);
      qs.x += a.x; qs.y += a.y; qs.z += a.z; qs.w += a.w;
      bs.x += c.x; bs.y += c.y; bs.z += c.z; bs.w += c.w;
    }
    qs.x = qs.x > 0.f ? qs.x : 0.f; qs.y = qs.y > 0.f ? qs.y : 0.f;
    qs.z = qs.z > 0.f ? qs.z : 0.f; qs.w = qs.w > 0.f ? qs.w : 0.f;
    *(float4*)(Y + i) = qs;
    float4 ob = {qs.x + bs.x, qs.y + bs.y, qs.z + bs.z, qs.w + bs.w};
    *(float4*)(out + i) = ob;
  }
  gbar(Bar, 2);

  // ---- stage C: forward — PA partials over 8-ci slice -----------------------
  {
    int ciS = blk & 15, ochP = (blk >> 4) & 7, b = blk >> 7;
    int och0 = ochP * 8 + wv * 2;
    const float* pb = Y + (size_t)(b * 128 + ciS * 8) * 1024;
    float wA0[10], wA1[10], wB0[10], wB1[10];
    float4 rA[6], rB[6];
    float acc0[16], acc1[16], dummy[16];
#pragma unroll
    for (int i = 0; i < 16; ++i) { acc0[i] = 0.f; acc1[i] = 0.f; }
    int ci0 = ciS * 8;
    load_rows6(pb, strip4, cg4, rA);
    wldF(Wfb, ci0, och0, wA0);
    wldF(Wfb, ci0, och0 + 1, wA1);
    for (int ci = 0; ci < 8; ci += 2) {
      load_rows6(pb + (size_t)(ci + 1) * 1024, strip4, cg4, rB);
      wldF(Wfb, ci0 + ci + 1, och0, wB0);
      wldF(Wfb, ci0 + ci + 1, och0 + 1, wB1);
      compute16x2<false, false>(rA, wA0, wA1, 0.f, strip4, cg0, cg7, acc0, acc1, dummy, dummy);
      if (ci + 2 < 8) {
        load_rows6(pb + (size_t)(ci + 2) * 1024, strip4, cg4, rA);
        wldF(Wfb, ci0 + ci + 2, och0, wA0);
        wldF(Wfb, ci0 + ci + 2, och0 + 1, wA1);
      }
      compute16x2<false, false>(rB, wB0, wB1, 0.f, strip4, cg0, cg7, acc0, acc1, dummy, dummy);
    }
    size_t off = (size_t)ciS * 262144 + (size_t)(b * 64 + och0) * 1024 + strip4 * 32 + cg4;
#pragma unroll
    for (int k = 0; k < 4; ++k) {
      *(float4*)(PA + off + k * 32) = {acc0[k*4], acc0[k*4+1], acc0[k*4+2], acc0[k*4+3]};
      *(float4*)(PA + off + 1024 + k * 32) = {acc1[k*4], acc1[k*4+1], acc1[k*4+2], acc1[k*4+3]};
    }
  }
  gbar(Bar, 3);

  // ---- stage D: vnorm (blocks 0..255 only; bit-identical to k_vnorm) --------
  if (blk < 256) {
    size_t i = (size_t)(blk * 256 + tid) * 4;
    float4 s = {0.f, 0.f, 0.f, 0.f};
#pragma unroll
    for (int o = 0; o < 16; ++o) {
      float4 q = *(const float4*)(PA + (size_t)o * 262144 + i);
      s.x += q.x; s.y += q.y; s.z += q.z; s.w += q.w;
    }
    float4 xv = *(const float4*)(x + i);
    float4 v = {xv.x - s.x, xv.y - s.y, xv.z - s.z, xv.w - s.w};
    *(float4*)(V + i) = v;
    float g = v.x * v.x + v.y * v.y + v.z * v.z + v.w * v.w;
#pragma unroll
    for (int d = 32; d; d >>= 1) g += __shfl_down(g, d, 64);
    if ((tid & 63) == 0) ws[tid >> 6] = g;
    __syncthreads();
    if (tid == 0) Gam[blk] = ws[0] + ws[1] + ws[2] + ws[3];
  }
  gbar(Bar, 4);

  // ---- stage E: finalize — Fp partials over 8-ci octant ---------------------
  {
    int ciO = blk & 7, coP = (blk >> 3) & 15, b = blk >> 7;
    int co0 = coP * 8 + wv * 2;
    float g = Gam[tid];
#pragma unroll
    for (int d = 32; d; d >>= 1) g += __shfl_down(g, d, 64);
    if ((tid & 63) == 0) ws[tid >> 6] = g;
    __syncthreads();
    float d0 = ((float)NUM_ITERS * LR_F) *
               __builtin_amdgcn_rsqf(ws[0] + ws[1] + ws[2] + ws[3]);
    const float* pb = V + (size_t)(b * 64 + ciO * 8) * 1024;
    float wA0[10], wA1[10], wB0[10], wB1[10];
    float4 rA[6], rB[6];
    float acc0[16], acc1[16], dummy[16];
#pragma unroll
    for (int i = 0; i < 16; ++i) { acc0[i] = 0.f; acc1[i] = 0.f; }
    int civ0 = ciO * 8;
    load_rows6(pb, strip4, cg4, rA);
    wldZ(Wfb, co0, civ0, wA0);
    wldZ(Wfb, co0 + 1, civ0, wA1);
    for (int ci = 0; ci < 8; ci += 2) {
      load_rows6(pb + (size_t)(ci + 1) * 1024, strip4, cg4, rB);
      wldZ(Wfb, co0, civ0 + ci + 1, wB0);
      wldZ(Wfb, co0 + 1, civ0 + ci + 1, wB1);
      compute16x2<false, true>(rA, wA0, wA1, d0, strip4, cg0, cg7, acc0, acc1, dummy, dummy);
      if (ci + 2 < 8) {
        load_rows6(pb + (size_t)(ci + 2) * 1024, strip4, cg4, rA);
        wldZ(Wfb, co0, civ0 + ci + 2, wA0);
        wldZ(Wfb, co0 + 1, civ0 + ci + 2, wA1);
      }
      compute16x2<false, true>(rB, wB0, wB1, d0, strip4, cg0, cg7, acc0, acc1, dummy, dummy);
    }
    size_t off = (size_t)ciO * 524288 + (size_t)(b * 128 + co0) * 1024 + strip4 * 32 + cg4;
#pragma unroll
    for (int k = 0; k < 4; ++k) {
      *(float4*)(Fp + off + k * 32) = {acc0[k*4], acc0[k*4+1], acc0[k*4+2], acc0[k*4+3]};
      *(float4*)(Fp + off + 1024 + k * 32) = {acc1[k*4], acc1[k*4+1], acc1[k*4+2], acc1[k*4+3]};
    }
  }
  gbar(Bar, 5);

  // ---- stage F: out += sum8 Fp ----------------------------------------------
  {
    size_t i = (size_t)(blk * 256 + tid) * 4;
    float4 s = *(const float4*)(out + i);
#pragma unroll
    for (int q = 0; q < 8; ++q) {
      float4 p = *(const float4*)(Fp + (size_t)q * 524288 + i);
      s.x += p.x; s.y += p.y; s.z += p.z; s.w += p.w;
    }
    *(float4*)(out + i) = s;
  }
}

// ---- launch -----------------------------------------------------------------
extern "C" void kernel_launch(void* const* d_in, const int* in_sizes, int n_in,
                              void* d_out, int out_size, void* d_ws, size_t ws_size,
                              hipStream_t stream) {
  const float* x   = (const float*)d_in[0];
  const float* Wff = (const float*)d_in[1];
  const float* Wfb = (const float*)d_in[2];
  const float* Wb  = (const float*)d_in[3];
  float* out = (float*)d_out;

  float* V    = (float*)d_ws;                  // 262144 (v0)
  float* Gam  = V + VPLANE;                    // 256 block partials
  float* PA   = Gam + 256;                     // 16 * 262144
  float* Q    = PA + (size_t)16 * 262144;      // 8 * 524288
  float* Bq   = Q + (size_t)8 * 524288;        // 8 * 524288
  float* Fp   = Bq + (size_t)8 * 524288;       // 8 * 524288
  float* Y    = Fp + (size_t)8 * 524288;       // 524288 (relu(sum Q))
  unsigned* Bar = (unsigned*)(Y + 524288);     // barrier counter (zeroed below)

  (void)hipMemsetAsync(Bar, 0, 256, stream);
  hipLaunchKernelGGL(k_fused, dim3(512), dim3(256), 0, stream,
                     x, Wff, Wfb, Wb, out, V, Gam, PA, Q, Bq, Fp, Y, Bar);
}

// Round 13
// 144.594 us; speedup vs baseline: 2.6519x; 2.6519x over previous
//
#include <hip/hip_runtime.h>

#define NUM_ITERS 500
#define LR_F 0.001f
// K=1 Krylov truncation: s = d0*v0, d0 = 500*LR/||v0||.
// R22: register-direct conv WIN. R24: och-pairing WIN (114.9). R25/R27:
//      pipelining/DPP ~neutral -> conv inner loop not the bottleneck.
// R26/R31: fusion closed (cooperative API breaks graph capture; hand-rolled
//      threadfence barrier costs ~40us/phase -> 324us). BUT R31's counters
//      exposed the real cost: WRITE_SIZE 72.8MB = partial buffers (Q/Bq/PA/
//      Fp). x is only 1MB (L2-trivial) -> ci-splitting was never needed.
// R32 (this round): FULL-REDUCTION restructure, split by ROWS not ci:
//      k_A: init conv + bypass + relu + out-base (64-ci in-block) -> Y,out.
//           Q/Bq deleted (-64MB traffic).
//      k_B: forward conv, ciH 2-split -> PA 2MB (was 16MB).
//      k_vnorm: V = x - (PA0+PA1), Gam block partials.
//      k_D: finalize conv (d0*v0, flipped W) += directly into out
//           (exclusive row regions, no atomics). Fp + k_fsum deleted.
//      Per-px tap order unchanged (di/dj/c asc, zero->scale->dpp->mask);
//      only ci-grouping of sums changes (~1e-5 << 0.121 threshold).

// ---- DPP lane+-1 within 16-lane rows (boundary lanes masked by caller) ------
__device__ __forceinline__ float dpp_shr1(float v) {   // lane L <- lane L-1
  int r = __builtin_amdgcn_update_dpp(0, __float_as_int(v), 0x111, 0xf, 0xf, true);
  return __int_as_float(r);
}
__device__ __forceinline__ float dpp_shl1(float v) {   // lane L <- lane L+1
  int r = __builtin_amdgcn_update_dpp(0, __float_as_int(v), 0x101, 0xf, 0xf, true);
  return __int_as_float(r);
}

// ---- ld3: rows row-1,row,row+1 of one plane (clamped, edges zeroed) ---------
__device__ __forceinline__ void ld3(const float* __restrict__ pl, int row,
                                    int cg4, bool top, bool bot, float4 r[3]) {
  r[0] = *(const float4*)(pl + (top ? 0 : row - 1) * 32 + cg4);
  r[1] = *(const float4*)(pl + row * 32 + cg4);
  r[2] = *(const float4*)(pl + (bot ? 31 : row + 1) * 32 + cg4);
  if (top) { r[0].x = 0.f; r[0].y = 0.f; r[0].z = 0.f; r[0].w = 0.f; }
  if (bot) { r[2].x = 0.f; r[2].y = 0.f; r[2].z = 0.f; r[2].w = 0.f; }
}

// ---- k_A: out-row conv3x3(x,Wff) full 64-ci + bypass + relu -----------------
// grid 256 = b(2b)|ochP(4b)|rowQ(2b); thread: 2 och x 4 px (1 row x 4 cols)
__global__ __launch_bounds__(256, 2) void k_A(const float* __restrict__ x,
                                              const float* __restrict__ Wff,
                                              const float* __restrict__ Wb,
                                              float* __restrict__ Y,
                                              float* __restrict__ out) {
  int tid = threadIdx.x, blk = blockIdx.x;
  int rowQ = blk & 3, ochP = (blk >> 2) & 15, b = blk >> 6;
  int wv = __builtin_amdgcn_readfirstlane(tid >> 6);
  int och0 = ochP * 8 + wv * 2;               // pair (och0, och0+1), 0..126
  int row = rowQ * 8 + ((tid >> 3) & 7);      // output row 0..31
  int cg = tid & 7, cg4 = cg * 4;
  bool cg0 = cg == 0, cg7 = cg == 7;
  bool top = row == 0, bot = row == 31;
  float acc0[4] = {0.f, 0.f, 0.f, 0.f}, acc1[4] = {0.f, 0.f, 0.f, 0.f};
  float by0[4] = {0.f, 0.f, 0.f, 0.f}, by1[4] = {0.f, 0.f, 0.f, 0.f};
  const float* pbase = x + (size_t)b * 65536;
  for (int ci = 0; ci < 64; ++ci) {
    float4 rr[3];
    ld3(pbase + (size_t)ci * 1024, row, cg4, top, bot, rr);
    const float* s0 = Wff + (size_t)(och0 * 64 + ci) * 9;
    const float* s1 = s0 + 64 * 9;
    float wb0 = Wb[och0 * 64 + ci], wb1 = Wb[(och0 + 1) * 64 + ci];
#pragma unroll
    for (int di = 0; di < 3; ++di) {
      float4 f4 = rr[di];
      float fl = dpp_shr1(f4.w);
      float fr = dpp_shl1(f4.x);
      fl = cg0 ? 0.f : fl;
      fr = cg7 ? 0.f : fr;
      float fv[6] = {fl, f4.x, f4.y, f4.z, f4.w, fr};
#pragma unroll
      for (int dj = 0; dj < 3; ++dj) {
        float w0 = s0[di * 3 + dj], w1 = s1[di * 3 + dj];
#pragma unroll
        for (int c = 0; c < 4; ++c) {
          acc0[c] = fmaf(fv[c + dj], w0, acc0[c]);
          acc1[c] = fmaf(fv[c + dj], w1, acc1[c]);
        }
      }
      if (di == 1) {
#pragma unroll
        for (int c = 0; c < 4; ++c) {
          by0[c] = fmaf(fv[c + 1], wb0, by0[c]);
          by1[c] = fmaf(fv[c + 1], wb1, by1[c]);
        }
      }
    }
  }
  size_t off = (size_t)(b * 128 + och0) * 1024 + row * 32 + cg4;
  float4 y0, y1, o0, o1;
  y0.x = acc0[0] > 0.f ? acc0[0] : 0.f; y0.y = acc0[1] > 0.f ? acc0[1] : 0.f;
  y0.z = acc0[2] > 0.f ? acc0[2] : 0.f; y0.w = acc0[3] > 0.f ? acc0[3] : 0.f;
  y1.x = acc1[0] > 0.f ? acc1[0] : 0.f; y1.y = acc1[1] > 0.f ? acc1[1] : 0.f;
  y1.z = acc1[2] > 0.f ? acc1[2] : 0.f; y1.w = acc1[3] > 0.f ? acc1[3] : 0.f;
  o0.x = y0.x + by0[0]; o0.y = y0.y + by0[1]; o0.z = y0.z + by0[2]; o0.w = y0.w + by0[3];
  o1.x = y1.x + by1[0]; o1.y = y1.y + by1[1]; o1.z = y1.z + by1[2]; o1.w = y1.w + by1[3];
  *(float4*)(Y + off) = y0;
  *(float4*)(out + off) = o0;
  *(float4*)(Y + off + 1024) = y1;
  *(float4*)(out + off + 1024) = o1;
}

// ---- k_B: forward conv3x3(Y, Wfb^T), 64-ci half-reduction -------------------
// grid 512 = b(2b)|ochP(4b)|rowQ(2b)|ciH(1b); thread: 1 och x 4 px
__global__ __launch_bounds__(256, 2) void k_B(const float* __restrict__ Y,
                                              const float* __restrict__ Wfb,
                                              float* __restrict__ PA) {
  int tid = threadIdx.x, blk = blockIdx.x;
  int ciH = blk & 1, rowQ = (blk >> 1) & 3, ochP = (blk >> 3) & 15, b = blk >> 7;
  int wv = __builtin_amdgcn_readfirstlane(tid >> 6);
  int och = ochP * 4 + wv;                    // 0..63
  int row = rowQ * 8 + ((tid >> 3) & 7);
  int cg = tid & 7, cg4 = cg * 4;
  bool cg0 = cg == 0, cg7 = cg == 7;
  bool top = row == 0, bot = row == 31;
  float acc[4] = {0.f, 0.f, 0.f, 0.f};
  const float* pbase = Y + (size_t)(b * 128 + ciH * 64) * 1024;
  int ci0 = ciH * 64;
  for (int cc = 0; cc < 64; ++cc) {
    float4 rr[3];
    ld3(pbase + (size_t)cc * 1024, row, cg4, top, bot, rr);
    const float* s = Wfb + (size_t)((ci0 + cc) * 64 + och) * 9;
#pragma unroll
    for (int di = 0; di < 3; ++di) {
      float4 f4 = rr[di];
      float fl = dpp_shr1(f4.w);
      float fr = dpp_shl1(f4.x);
      fl = cg0 ? 0.f : fl;
      fr = cg7 ? 0.f : fr;
      float fv[6] = {fl, f4.x, f4.y, f4.z, f4.w, fr};
#pragma unroll
      for (int dj = 0; dj < 3; ++dj) {
        float w = s[di * 3 + dj];
#pragma unroll
        for (int c = 0; c < 4; ++c)
          acc[c] = fmaf(fv[c + dj], w, acc[c]);
      }
    }
  }
  size_t off = (size_t)ciH * 262144 + (size_t)(b * 64 + och) * 1024 + row * 32 + cg4;
  float4 o = {acc[0], acc[1], acc[2], acc[3]};
  *(float4*)(PA + off) = o;
}

// ---- k_vnorm: v0 = x - (PA0+PA1); Gam[blk] = block partial of ||v0||^2 ------
__global__ __launch_bounds__(256) void k_vnorm(const float* __restrict__ x,
                                               const float* __restrict__ PA,
                                               float* __restrict__ v0out,
                                               float* __restrict__ Gam) {
  __shared__ float ws[4];
  int tid = threadIdx.x;
  size_t i = (size_t)(blockIdx.x * 256 + tid) * 4;
  float4 p0 = *(const float4*)(PA + i);
  float4 p1 = *(const float4*)(PA + 262144 + i);
  float4 xv = *(const float4*)(x + i);
  float4 v = {xv.x - (p0.x + p1.x), xv.y - (p0.y + p1.y),
              xv.z - (p0.z + p1.z), xv.w - (p0.w + p1.w)};
  *(float4*)(v0out + i) = v;
  float g = v.x * v.x + v.y * v.y + v.z * v.z + v.w * v.w;
#pragma unroll
  for (int d = 32; d; d >>= 1) g += __shfl_down(g, d, 64);
  if ((tid & 63) == 0) ws[tid >> 6] = g;
  __syncthreads();
  if (tid == 0) Gam[blockIdx.x] = ws[0] + ws[1] + ws[2] + ws[3];
}

// ---- k_D: finalize conv3x3(d0*v0, flip(Wfb)) full 64-ci, out += -------------
// grid 256 = b(2b)|coP(4b)|rowQ(2b); thread: 2 co x 4 px. Exclusive regions.
__global__ __launch_bounds__(256, 2) void k_D(const float* __restrict__ V,
                                              const float* __restrict__ Gam,
                                              const float* __restrict__ Wfb,
                                              float* __restrict__ out) {
  __shared__ float ws[4];
  int tid = threadIdx.x, blk = blockIdx.x;
  int rowQ = blk & 3, coP = (blk >> 2) & 15, b = blk >> 6;
  int wv = __builtin_amdgcn_readfirstlane(tid >> 6);
  int co0 = coP * 8 + wv * 2;                 // 0..126
  int row = rowQ * 8 + ((tid >> 3) & 7);
  int cg = tid & 7, cg4 = cg * 4;
  bool cg0 = cg == 0, cg7 = cg == 7;
  bool top = row == 0, bot = row == 31;
  // reduce Gam[0..255] -> d0
  float g = Gam[tid];
#pragma unroll
  for (int d = 32; d; d >>= 1) g += __shfl_down(g, d, 64);
  if ((tid & 63) == 0) ws[tid >> 6] = g;
  __syncthreads();
  float d0 = ((float)NUM_ITERS * LR_F) *
             __builtin_amdgcn_rsqf(ws[0] + ws[1] + ws[2] + ws[3]);
  float acc0[4] = {0.f, 0.f, 0.f, 0.f}, acc1[4] = {0.f, 0.f, 0.f, 0.f};
  const float* pbase = V + (size_t)b * 65536;
  for (int ci = 0; ci < 64; ++ci) {
    float4 rr[3];
    ld3(pbase + (size_t)ci * 1024, row, cg4, top, bot, rr);
    const float* s0 = Wfb + (size_t)(co0 * 64 + ci) * 9;
    const float* s1 = s0 + 64 * 9;
#pragma unroll
    for (int di = 0; di < 3; ++di) {
      float4 f4 = rr[di];
      f4.x *= d0; f4.y *= d0; f4.z *= d0; f4.w *= d0;
      float fl = dpp_shr1(f4.w);
      float fr = dpp_shl1(f4.x);
      fl = cg0 ? 0.f : fl;
      fr = cg7 ? 0.f : fr;
      float fv[6] = {fl, f4.x, f4.y, f4.z, f4.w, fr};
#pragma unroll
      for (int dj = 0; dj < 3; ++dj) {
        float w0 = s0[8 - (di * 3 + dj)];     // tap-flipped
        float w1 = s1[8 - (di * 3 + dj)];
#pragma unroll
        for (int c = 0; c < 4; ++c) {
          acc0[c] = fmaf(fv[c + dj], w0, acc0[c]);
          acc1[c] = fmaf(fv[c + dj], w1, acc1[c]);
        }
      }
    }
  }
  size_t off = (size_t)(b * 128 + co0) * 1024 + row * 32 + cg4;
  float4 o0 = *(const float4*)(out + off);
  float4 o1 = *(const float4*)(out + off + 1024);
  o0.x += acc0[0]; o0.y += acc0[1]; o0.z += acc0[2]; o0.w += acc0[3];
  o1.x += acc1[0]; o1.y += acc1[1]; o1.z += acc1[2]; o1.w += acc1[3];
  *(float4*)(out + off) = o0;
  *(float4*)(out + off + 1024) = o1;
}

// ---- launch -----------------------------------------------------------------
extern "C" void kernel_launch(void* const* d_in, const int* in_sizes, int n_in,
                              void* d_out, int out_size, void* d_ws, size_t ws_size,
                              hipStream_t stream) {
  const float* x   = (const float*)d_in[0];
  const float* Wff = (const float*)d_in[1];
  const float* Wfb = (const float*)d_in[2];
  const float* Wb  = (const float*)d_in[3];
  float* out = (float*)d_out;

  float* Y    = (float*)d_ws;                  // 524288 (relu(conv1) full)
  float* PA   = Y + 524288;                    // 2 * 262144 (forward halves)
  float* V    = PA + 2 * 262144;               // 262144 (v0)
  float* Gam  = V + 262144;                    // 256 block partials

  hipLaunchKernelGGL(k_A,     dim3(256), dim3(256), 0, stream, x, Wff, Wb, Y, out);
  hipLaunchKernelGGL(k_B,     dim3(512), dim3(256), 0, stream, Y, Wfb, PA);
  hipLaunchKernelGGL(k_vnorm, dim3(256), dim3(256), 0, stream, x, PA, V, Gam);
  hipLaunchKernelGGL(k_D,     dim3(256), dim3(256), 0, stream, V, Gam, Wfb, out);
}